// Round 1
// baseline (7015.918 us; speedup 1.0000x reference)
//
#include <hip/hip_runtime.h>

#define EMB 128
#define N_ITEMS 50000
#define N_SESS 50000
#define N_TOTAL 100000
#define NNZ_S 500000
#define NNZ_A 3200000
#define BATCH 2048
#define N_SCORE 50000

// ---------------- kernel 1: gather x_item = emb_table[item_emb_idxes] ----------------
// one float4 per thread, 32 float4 per row
__global__ void k_gather_items(const float* __restrict__ emb, const int* __restrict__ idx,
                               float* __restrict__ x_item) {
    int t = blockIdx.x * blockDim.x + threadIdx.x;
    int i = t >> 5;
    int d = (t & 31) << 2;
    if (i >= N_ITEMS) return;
    float4 v = *(const float4*)(emb + (long)idx[i] * EMB + d);
    *(float4*)(x_item + (long)i * EMB + d) = v;
}

// ---------------- COO SpMM via atomics: dst[rows[e]] += vals[e] * src[cols[e]] ----------------
// half-wave (32 lanes) per nnz, float4 per lane
__global__ void k_spmm_atomic(const float* __restrict__ vals, const int* __restrict__ rows,
                              const int* __restrict__ cols, const float* __restrict__ src,
                              float* __restrict__ dst, int nnz) {
    long t = (long)blockIdx.x * blockDim.x + threadIdx.x;
    long e = t >> 5;
    int d = (int)(t & 31) << 2;
    if (e >= nnz) return;
    float v = vals[e];
    int r = rows[e];
    int c = cols[e];
    float4 s = *(const float4*)(src + (long)c * EMB + d);
    float* p = dst + (long)r * EMB + d;
    atomicAdd(p + 0, v * s.x);
    atomicAdd(p + 1, v * s.y);
    atomicAdd(p + 2, v * s.z);
    atomicAdd(p + 3, v * s.w);
}

// ---------------- xw = x @ W   ([N_TOTAL,128] x [128,128]) ----------------
// block: 256 threads, 16 rows per block. W fully staged in LDS (64KB), X tile 8KB.
__global__ __launch_bounds__(256) void k_gemm_xw(const float* __restrict__ x,
                                                 const float* __restrict__ W,
                                                 float* __restrict__ xw) {
    __shared__ float Wl[128 * 128]; // 64 KB, [k][col]
    __shared__ float Xs[16][128];   // 8 KB
    int tid = threadIdx.x;
    for (int i = tid * 4; i < 128 * 128; i += 256 * 4) {
        *(float4*)(Wl + i) = *(const float4*)(W + i);
    }
    int row0 = blockIdx.x * 16; // N_TOTAL % 16 == 0
    for (int i = tid * 4; i < 16 * 128; i += 256 * 4) {
        int r = i >> 7, d = i & 127;
        *(float4*)(&Xs[r][d]) = *(const float4*)(x + (long)(row0 + r) * EMB + d);
    }
    __syncthreads();
    int col = tid & 127;
    int rg = tid >> 7; // 0/1, 8 rows each
    float acc[8] = {0, 0, 0, 0, 0, 0, 0, 0};
    for (int k = 0; k < 128; ++k) {
        float w = Wl[k * 128 + col];
#pragma unroll
        for (int r = 0; r < 8; ++r) acc[r] += Xs[rg * 8 + r][k] * w;
    }
#pragma unroll
    for (int r = 0; r < 8; ++r)
        xw[(long)(row0 + rg * 8 + r) * EMB + col] = acc[r];
}

// ---------------- h1 += b (broadcast bias) ----------------
__global__ void k_bias_add(float* __restrict__ h1, const float* __restrict__ b) {
    long t = (long)blockIdx.x * blockDim.x + threadIdx.x;
    if (t >= (long)N_TOTAL * EMB) return;
    h1[t] += b[t & 127];
}

// ---------------- gather rows of h1 ----------------
__global__ void k_gather_h(const float* __restrict__ h1, const int* __restrict__ idx,
                           float* __restrict__ dst, int n) {
    int t = blockIdx.x * blockDim.x + threadIdx.x;
    int i = t >> 5;
    int d = (t & 31) << 2;
    if (i >= n) return;
    float4 v = *(const float4*)(h1 + (long)idx[i] * EMB + d);
    *(float4*)(dst + (long)i * EMB + d) = v;
}

// ---------------- out[2048, 50000] = hb @ hi^T ----------------
// 64x64 tile / block, 256 threads, 4x4 micro-tile, K=128 fully in LDS.
#define BM 64
#define BN 64
__global__ __launch_bounds__(256) void k_score_gemm(const float* __restrict__ A,
                                                    const float* __restrict__ B,
                                                    float* __restrict__ C) {
    __shared__ float As[BM][129];
    __shared__ float Bs[BN][129];
    int tid = threadIdx.x;
    int row0 = blockIdx.y * BM; // 2048 % 64 == 0, no guard
    int col0 = blockIdx.x * BN; // 50000 % 64 != 0, guard cols

    for (int i = tid * 4; i < BM * 128; i += 256 * 4) {
        int r = i >> 7, d = i & 127;
        *(float4*)(&As[r][d]) = *(const float4*)(A + (long)(row0 + r) * EMB + d);
    }
    for (int i = tid * 4; i < BN * 128; i += 256 * 4) {
        int r = i >> 7, d = i & 127;
        float4 v = make_float4(0.f, 0.f, 0.f, 0.f);
        if (col0 + r < N_SCORE) v = *(const float4*)(B + (long)(col0 + r) * EMB + d);
        *(float4*)(&Bs[r][d]) = v;
    }
    __syncthreads();

    int tr = tid >> 4;  // 0..15
    int tc = tid & 15;  // 0..15
    float acc[4][4] = {};
    for (int k = 0; k < 128; ++k) {
        float a[4], b[4];
#pragma unroll
        for (int i = 0; i < 4; ++i) a[i] = As[tr * 4 + i][k];
#pragma unroll
        for (int j = 0; j < 4; ++j) b[j] = Bs[tc * 4 + j][k];
#pragma unroll
        for (int i = 0; i < 4; ++i)
#pragma unroll
            for (int j = 0; j < 4; ++j) acc[i][j] += a[i] * b[j];
    }
#pragma unroll
    for (int i = 0; i < 4; ++i) {
        long r = row0 + tr * 4 + i;
#pragma unroll
        for (int j = 0; j < 4; ++j) {
            int c = col0 + tc * 4 + j;
            if (c < N_SCORE) C[r * N_SCORE + c] = acc[i][j];
        }
    }
}

extern "C" void kernel_launch(void* const* d_in, const int* in_sizes, int n_in,
                              void* d_out, int out_size, void* d_ws, size_t ws_size,
                              hipStream_t stream) {
    const float* emb_table      = (const float*)d_in[0];
    const float* W              = (const float*)d_in[1];
    const float* b              = (const float*)d_in[2];
    const float* sess_vals      = (const float*)d_in[3];
    const float* A_vals         = (const float*)d_in[4];
    const int*   batch_idxes    = (const int*)d_in[5];
    const int*   item_idxes     = (const int*)d_in[6];
    const int*   item_emb_idxes = (const int*)d_in[7];
    const int*   sess_rows      = (const int*)d_in[8];
    const int*   sess_cols      = (const int*)d_in[9];
    const int*   A_rows         = (const int*)d_in[10];
    const int*   A_cols         = (const int*)d_in[11];
    float* out = (float*)d_out;

    // workspace layout (floats)
    float* ws = (float*)d_ws;
    float* x   = ws;                                  // [N_TOTAL,128]  (session rows then item rows)
    float* xw  = ws + (long)N_TOTAL * EMB;            // [N_TOTAL,128]
    float* h1  = ws + 2L * N_TOTAL * EMB;             // [N_TOTAL,128]
    // hb/hi overlay the x region (dead after k_gemm_xw)
    float* hb  = x;                                   // [BATCH,128]
    float* hi  = x + (long)BATCH * EMB;               // [N_SCORE,128]

    float* x_session = x;                      // rows [0, N_SESS)
    float* x_item    = x + (long)N_SESS * EMB; // rows [N_SESS, N_TOTAL)

    // 1. zero x_session
    hipMemsetAsync(x_session, 0, (size_t)N_SESS * EMB * sizeof(float), stream);
    // 2. gather items
    k_gather_items<<<(N_ITEMS * 32 + 255) / 256, 256, 0, stream>>>(emb_table, item_emb_idxes, x_item);
    // 3. spmm1: x_session = segsum(sess_vals * x_item[sess_cols])
    k_spmm_atomic<<<(int)(((long)NNZ_S * 32 + 255) / 256), 256, 0, stream>>>(
        sess_vals, sess_rows, sess_cols, x_item, x_session, NNZ_S);
    // 4. xw = x @ W
    k_gemm_xw<<<N_TOTAL / 16, 256, 0, stream>>>(x, W, xw);
    // 5. zero h1, spmm2: h1 = segsum(A_vals * xw[A_cols])
    hipMemsetAsync(h1, 0, (size_t)N_TOTAL * EMB * sizeof(float), stream);
    k_spmm_atomic<<<(int)(((long)NNZ_A * 32 + 255) / 256), 256, 0, stream>>>(
        A_vals, A_rows, A_cols, xw, h1, NNZ_A);
    // 6. h1 += b
    k_bias_add<<<(int)(((long)N_TOTAL * EMB + 255) / 256), 256, 0, stream>>>(h1, b);
    // 7. gather hb, hi
    k_gather_h<<<(BATCH * 32 + 255) / 256, 256, 0, stream>>>(h1, batch_idxes, hb, BATCH);
    k_gather_h<<<(N_SCORE * 32 + 255) / 256, 256, 0, stream>>>(h1, item_idxes, hi, N_SCORE);
    // 8. out = hb @ hi^T
    dim3 grid((N_SCORE + BN - 1) / BN, BATCH / BM);
    k_score_gemm<<<grid, 256, 0, stream>>>(hb, hi, out);
}

// Round 2
// 1538.216 us; speedup vs baseline: 4.5611x; 4.5611x over previous
//
#include <hip/hip_runtime.h>

#define EMB 128
#define N_ITEMS 50000
#define N_SESS 50000
#define N_TOTAL 100000
#define NNZ_S 500000
#define NNZ_A 3200000
#define BATCH 2048
#define N_SCORE 50000

// ---------------- gather x_item = emb_table[item_emb_idxes] ----------------
__global__ void k_gather_items(const float* __restrict__ emb, const int* __restrict__ idx,
                               float* __restrict__ x_item) {
    int t = blockIdx.x * blockDim.x + threadIdx.x;
    int i = t >> 5;
    int d = (t & 31) << 2;
    if (i >= N_ITEMS) return;
    float4 v = *(const float4*)(emb + (long)idx[i] * EMB + d);
    *(float4*)(x_item + (long)i * EMB + d) = v;
}

// ---------------- CSR build: histogram ----------------
__global__ void k_count(const int* __restrict__ rows, int* __restrict__ cnt, int nnz) {
    int e = blockIdx.x * 256 + threadIdx.x;
    if (e < nnz) atomicAdd(&cnt[rows[e]], 1);
}

// ---------------- CSR build: single-block exclusive scan (n up to ~100K) ----------------
__global__ __launch_bounds__(1024) void k_scan_excl(const int* __restrict__ cnt,
                                                    int* __restrict__ off, int n) {
    __shared__ int wsum[16];
    __shared__ int carry_s;
    int tid = threadIdx.x, lane = tid & 63, wid = tid >> 6;
    if (tid == 0) carry_s = 0;
    __syncthreads();
    for (int base = 0; base < n; base += 1024) {
        int i = base + tid;
        int v = (i < n) ? cnt[i] : 0;
        int x = v;
#pragma unroll
        for (int s = 1; s < 64; s <<= 1) {
            int t = __shfl_up(x, s, 64);
            if (lane >= s) x += t;
        }
        if (lane == 63) wsum[wid] = x;
        __syncthreads();
        if (wid == 0) {
            int y = (lane < 16) ? wsum[lane] : 0;
#pragma unroll
            for (int s = 1; s < 16; s <<= 1) {
                int t = __shfl_up(y, s, 64);
                if (lane >= s) y += t;
            }
            if (lane < 16) wsum[lane] = y;
        }
        __syncthreads();
        int carry = carry_s;
        int wofs = (wid == 0) ? 0 : wsum[wid - 1];
        if (i < n) off[i] = carry + wofs + x - v; // exclusive
        __syncthreads();
        if (tid == 0) carry_s = carry + wsum[15];
        __syncthreads();
    }
}

// ---------------- CSR build: place edges (advances off[r] to inclusive) ----------------
__global__ void k_place(const int* __restrict__ rows, const int* __restrict__ cols,
                        const float* __restrict__ vals, int* __restrict__ off,
                        int* __restrict__ ecol, float* __restrict__ eval, int nnz) {
    int e = blockIdx.x * 256 + threadIdx.x;
    if (e < nnz) {
        int r = rows[e];
        int pos = atomicAdd(&off[r], 1);
        ecol[pos] = cols[e];
        eval[pos] = vals[e];
    }
}

// ---------------- CSR SpMM: one wave per row, lane owns 2 dims ----------------
// after k_place, off[r] = inclusive end; begin(r) = r ? off[r-1] : 0
__global__ __launch_bounds__(256) void k_spmm_csr(const int* __restrict__ off,
                                                  const int* __restrict__ ecol,
                                                  const float* __restrict__ eval,
                                                  const float* __restrict__ src,
                                                  float* __restrict__ dst,
                                                  const float* __restrict__ bias,
                                                  int nrows) {
    int r = (blockIdx.x * 256 + threadIdx.x) >> 6;
    int lane = threadIdx.x & 63;
    if (r >= nrows) return;
    int begin = (r == 0) ? 0 : off[r - 1];
    int end = off[r];
    float2 acc = make_float2(0.f, 0.f);
    int e = begin;
    for (; e + 2 <= end; e += 2) {
        float v0 = eval[e], v1 = eval[e + 1];
        int c0 = ecol[e], c1 = ecol[e + 1];
        float2 s0 = *(const float2*)(src + (long)c0 * EMB + lane * 2);
        float2 s1 = *(const float2*)(src + (long)c1 * EMB + lane * 2);
        acc.x += v0 * s0.x + v1 * s1.x;
        acc.y += v0 * s0.y + v1 * s1.y;
    }
    if (e < end) {
        float v0 = eval[e];
        int c0 = ecol[e];
        float2 s0 = *(const float2*)(src + (long)c0 * EMB + lane * 2);
        acc.x += v0 * s0.x;
        acc.y += v0 * s0.y;
    }
    if (bias) {
        acc.x += bias[lane * 2];
        acc.y += bias[lane * 2 + 1];
    }
    *(float2*)(dst + (long)r * EMB + lane * 2) = acc;
}

// ---------------- xw = x @ W   ([N_TOTAL,128] x [128,128]) ----------------
__global__ __launch_bounds__(256) void k_gemm_xw(const float* __restrict__ x,
                                                 const float* __restrict__ W,
                                                 float* __restrict__ xw) {
    __shared__ float Wl[128 * 128]; // 64 KB, [k][col]
    __shared__ float Xs[16][128];   // 8 KB
    int tid = threadIdx.x;
    for (int i = tid * 4; i < 128 * 128; i += 256 * 4) {
        *(float4*)(Wl + i) = *(const float4*)(W + i);
    }
    int row0 = blockIdx.x * 16;
    for (int i = tid * 4; i < 16 * 128; i += 256 * 4) {
        int r = i >> 7, d = i & 127;
        *(float4*)(&Xs[r][d]) = *(const float4*)(x + (long)(row0 + r) * EMB + d);
    }
    __syncthreads();
    int col = tid & 127;
    int rg = tid >> 7;
    float acc[8] = {0, 0, 0, 0, 0, 0, 0, 0};
    for (int k = 0; k < 128; ++k) {
        float w = Wl[k * 128 + col];
#pragma unroll
        for (int r = 0; r < 8; ++r) acc[r] += Xs[rg * 8 + r][k] * w;
    }
#pragma unroll
    for (int r = 0; r < 8; ++r)
        xw[(long)(row0 + rg * 8 + r) * EMB + col] = acc[r];
}

// ---------------- gather rows of h1 ----------------
__global__ void k_gather_h(const float* __restrict__ h1, const int* __restrict__ idx,
                           float* __restrict__ dst, int n) {
    int t = blockIdx.x * blockDim.x + threadIdx.x;
    int i = t >> 5;
    int d = (t & 31) << 2;
    if (i >= n) return;
    float4 v = *(const float4*)(h1 + (long)idx[i] * EMB + d);
    *(float4*)(dst + (long)i * EMB + d) = v;
}

// ---------------- out[2048, 50000] = hb @ hi^T ----------------
#define BM 64
#define BN 64
__global__ __launch_bounds__(256) void k_score_gemm(const float* __restrict__ A,
                                                    const float* __restrict__ B,
                                                    float* __restrict__ C) {
    __shared__ float As[BM][129];
    __shared__ float Bs[BN][129];
    int tid = threadIdx.x;
    int row0 = blockIdx.y * BM;
    int col0 = blockIdx.x * BN;

    for (int i = tid * 4; i < BM * 128; i += 256 * 4) {
        int r = i >> 7, d = i & 127;
        *(float4*)(&As[r][d]) = *(const float4*)(A + (long)(row0 + r) * EMB + d);
    }
    for (int i = tid * 4; i < BN * 128; i += 256 * 4) {
        int r = i >> 7, d = i & 127;
        float4 v = make_float4(0.f, 0.f, 0.f, 0.f);
        if (col0 + r < N_SCORE) v = *(const float4*)(B + (long)(col0 + r) * EMB + d);
        *(float4*)(&Bs[r][d]) = v;
    }
    __syncthreads();

    int tr = tid >> 4;
    int tc = tid & 15;
    float acc[4][4] = {};
    for (int k = 0; k < 128; ++k) {
        float a[4], b[4];
#pragma unroll
        for (int i = 0; i < 4; ++i) a[i] = As[tr * 4 + i][k];
#pragma unroll
        for (int j = 0; j < 4; ++j) b[j] = Bs[tc * 4 + j][k];
#pragma unroll
        for (int i = 0; i < 4; ++i)
#pragma unroll
            for (int j = 0; j < 4; ++j) acc[i][j] += a[i] * b[j];
    }
#pragma unroll
    for (int i = 0; i < 4; ++i) {
        long r = row0 + tr * 4 + i;
#pragma unroll
        for (int j = 0; j < 4; ++j) {
            int c = col0 + tc * 4 + j;
            if (c < N_SCORE) C[r * N_SCORE + c] = acc[i][j];
        }
    }
}

extern "C" void kernel_launch(void* const* d_in, const int* in_sizes, int n_in,
                              void* d_out, int out_size, void* d_ws, size_t ws_size,
                              hipStream_t stream) {
    const float* emb_table      = (const float*)d_in[0];
    const float* W              = (const float*)d_in[1];
    const float* b              = (const float*)d_in[2];
    const float* sess_vals      = (const float*)d_in[3];
    const float* A_vals         = (const float*)d_in[4];
    const int*   batch_idxes    = (const int*)d_in[5];
    const int*   item_idxes     = (const int*)d_in[6];
    const int*   item_emb_idxes = (const int*)d_in[7];
    const int*   sess_rows      = (const int*)d_in[8];
    const int*   sess_cols      = (const int*)d_in[9];
    const int*   A_rows         = (const int*)d_in[10];
    const int*   A_cols         = (const int*)d_in[11];
    float* out = (float*)d_out;

    // -------- workspace layout (floats), peak = 153.6 MB (3 x 51.2MB regions) --------
    float* ws = (float*)d_ws;
    float* x  = ws;                         // R0: [N_TOTAL,128]
    float* xw = ws + 12800000L;             // R1: [N_TOTAL,128]
    float* h1 = ws + 25600000L;             // R2: [N_TOTAL,128]

    float* x_session = x;                       // rows [0, N_SESS)
    float* x_item    = x + (long)N_SESS * EMB;  // rows [N_SESS, N_TOTAL)

    // R2 overlays (live only BEFORE h1 is produced): session CSR
    float* evS  = h1;                           // 500000 floats
    int*   ecS  = (int*)(h1 + 500000);          // 500000 ints
    int*   cntS = (int*)(h1 + 1000000);         // 50001 (pad to 50004)
    int*   offS = (int*)(h1 + 1050004);         // 50001

    // R0 overlays (live only AFTER x is consumed by x@W): A CSR
    float* evA  = x;                            // 3200000 floats
    int*   ecA  = (int*)(x + 3200000);          // 3200000 ints
    int*   cntA = (int*)(x + 6400000);          // 100001 (pad to 100004)
    int*   offA = (int*)(x + 6500004);          // 100001

    // R1 overlays (live only AFTER xw is consumed by spmm2)
    float* hb = xw;                             // [BATCH,128]
    float* hi = xw + (long)BATCH * EMB;         // [N_SCORE,128]

    // -------- 1. session CSR build (into R2) --------
    hipMemsetAsync(cntS, 0, (size_t)N_SESS * sizeof(int), stream);
    k_count<<<(NNZ_S + 255) / 256, 256, 0, stream>>>(sess_rows, cntS, NNZ_S);
    k_scan_excl<<<1, 1024, 0, stream>>>(cntS, offS, N_SESS);
    k_place<<<(NNZ_S + 255) / 256, 256, 0, stream>>>(sess_rows, sess_cols, sess_vals,
                                                     offS, ecS, evS, NNZ_S);
    // -------- 2. gather item embeddings (R0 upper half) --------
    k_gather_items<<<(N_ITEMS * 32 + 255) / 256, 256, 0, stream>>>(emb_table, item_emb_idxes, x_item);
    // -------- 3. spmm1: x_session (R0 lower half) --------
    k_spmm_csr<<<(N_SESS + 3) / 4, 256, 0, stream>>>(offS, ecS, evS, x_item, x_session,
                                                     nullptr, N_SESS);
    // -------- 4. xw = x @ W (R0 -> R1); x dead afterwards --------
    k_gemm_xw<<<N_TOTAL / 16, 256, 0, stream>>>(x, W, xw);
    // -------- 5. A CSR build (into R0, now dead) --------
    hipMemsetAsync(cntA, 0, (size_t)N_TOTAL * sizeof(int), stream);
    k_count<<<(NNZ_A + 255) / 256, 256, 0, stream>>>(A_rows, cntA, NNZ_A);
    k_scan_excl<<<1, 1024, 0, stream>>>(cntA, offA, N_TOTAL);
    k_place<<<(NNZ_A + 255) / 256, 256, 0, stream>>>(A_rows, A_cols, A_vals,
                                                     offA, ecA, evA, NNZ_A);
    // -------- 6. spmm2 + fused bias: h1 (R2); xw dead afterwards --------
    k_spmm_csr<<<(N_TOTAL + 3) / 4, 256, 0, stream>>>(offA, ecA, evA, xw, h1, b, N_TOTAL);
    // -------- 7. gather hb, hi (into R1, now dead) --------
    k_gather_h<<<(BATCH * 32 + 255) / 256, 256, 0, stream>>>(h1, batch_idxes, hb, BATCH);
    k_gather_h<<<(N_SCORE * 32 + 255) / 256, 256, 0, stream>>>(h1, item_idxes, hi, N_SCORE);
    // -------- 8. out = hb @ hi^T --------
    dim3 grid((N_SCORE + BN - 1) / BN, BATCH / BM);
    k_score_gemm<<<grid, 256, 0, stream>>>(hb, hi, out);
}

// Round 3
// 1090.873 us; speedup vs baseline: 6.4315x; 1.4101x over previous
//
#include <hip/hip_runtime.h>

#define EMB 128
#define N_ITEMS 50000
#define N_SESS 50000
#define N_TOTAL 100000
#define NNZ_S 500000
#define NNZ_A 3200000
#define BATCH 2048
#define N_SCORE 50000

typedef __attribute__((ext_vector_type(8))) short bf16x8;
typedef __attribute__((ext_vector_type(4))) float f32x4;

__device__ inline ushort f2bf(float f) {
    unsigned u = __float_as_uint(f);
    unsigned r = (u + 0x7fff + ((u >> 16) & 1)) >> 16;
    return (ushort)r;
}

// ---------------- gather x_item = emb_table[item_emb_idxes] (fp32) ----------------
__global__ void k_gather_items(const float* __restrict__ emb, const int* __restrict__ idx,
                               float* __restrict__ x_item) {
    int t = blockIdx.x * blockDim.x + threadIdx.x;
    int i = t >> 5;
    int d = (t & 31) << 2;
    if (i >= N_ITEMS) return;
    float4 v = *(const float4*)(emb + (long)idx[i] * EMB + d);
    *(float4*)(x_item + (long)i * EMB + d) = v;
}

// ---------------- CSR build: histogram ----------------
__global__ void k_count(const int* __restrict__ rows, int* __restrict__ cnt, int nnz) {
    int e = blockIdx.x * 256 + threadIdx.x;
    if (e < nnz) atomicAdd(&cnt[rows[e]], 1);
}

// ---------------- CSR build: single-block exclusive scan ----------------
__global__ __launch_bounds__(1024) void k_scan_excl(const int* __restrict__ cnt,
                                                    int* __restrict__ off, int n) {
    __shared__ int wsum[16];
    __shared__ int carry_s;
    int tid = threadIdx.x, lane = tid & 63, wid = tid >> 6;
    if (tid == 0) carry_s = 0;
    __syncthreads();
    for (int base = 0; base < n; base += 1024) {
        int i = base + tid;
        int v = (i < n) ? cnt[i] : 0;
        int x = v;
#pragma unroll
        for (int s = 1; s < 64; s <<= 1) {
            int t = __shfl_up(x, s, 64);
            if (lane >= s) x += t;
        }
        if (lane == 63) wsum[wid] = x;
        __syncthreads();
        if (wid == 0) {
            int y = (lane < 16) ? wsum[lane] : 0;
#pragma unroll
            for (int s = 1; s < 16; s <<= 1) {
                int t = __shfl_up(y, s, 64);
                if (lane >= s) y += t;
            }
            if (lane < 16) wsum[lane] = y;
        }
        __syncthreads();
        int carry = carry_s;
        int wofs = (wid == 0) ? 0 : wsum[wid - 1];
        if (i < n) off[i] = carry + wofs + x - v; // exclusive
        __syncthreads();
        if (tid == 0) carry_s = carry + wsum[15];
        __syncthreads();
    }
}

// ---------------- CSR build: place edges (advances off[r] to inclusive) ----------------
__global__ void k_place(const int* __restrict__ rows, const int* __restrict__ cols,
                        const float* __restrict__ vals, int* __restrict__ off,
                        int* __restrict__ ecol, float* __restrict__ eval, int nnz) {
    int e = blockIdx.x * 256 + threadIdx.x;
    if (e < nnz) {
        int r = rows[e];
        int pos = atomicAdd(&off[r], 1);
        ecol[pos] = cols[e];
        eval[pos] = vals[e];
    }
}

// ---------------- CSR SpMM: one wave per row, lane owns 2 dims ----------------
__global__ __launch_bounds__(256) void k_spmm_csr(const int* __restrict__ off,
                                                  const int* __restrict__ ecol,
                                                  const float* __restrict__ eval,
                                                  const float* __restrict__ src,
                                                  float* __restrict__ dst,
                                                  const float* __restrict__ bias,
                                                  int nrows) {
    int r = (blockIdx.x * 256 + threadIdx.x) >> 6;
    int lane = threadIdx.x & 63;
    if (r >= nrows) return;
    int begin = (r == 0) ? 0 : off[r - 1];
    int end = off[r];
    float2 acc = make_float2(0.f, 0.f);
    int e = begin;
    for (; e + 2 <= end; e += 2) {
        float v0 = eval[e], v1 = eval[e + 1];
        int c0 = ecol[e], c1 = ecol[e + 1];
        float2 s0 = *(const float2*)(src + (long)c0 * EMB + lane * 2);
        float2 s1 = *(const float2*)(src + (long)c1 * EMB + lane * 2);
        acc.x += v0 * s0.x + v1 * s1.x;
        acc.y += v0 * s0.y + v1 * s1.y;
    }
    if (e < end) {
        float v0 = eval[e];
        int c0 = ecol[e];
        float2 s0 = *(const float2*)(src + (long)c0 * EMB + lane * 2);
        acc.x += v0 * s0.x;
        acc.y += v0 * s0.y;
    }
    if (bias) {
        acc.x += bias[lane * 2];
        acc.y += bias[lane * 2 + 1];
    }
    *(float2*)(dst + (long)r * EMB + lane * 2) = acc;
}

// ---------------- xw = x @ W   ([N_TOTAL,128] x [128,128], fp32) ----------------
__global__ __launch_bounds__(256) void k_gemm_xw(const float* __restrict__ x,
                                                 const float* __restrict__ W,
                                                 float* __restrict__ xw) {
    __shared__ float Wl[128 * 128];
    __shared__ float Xs[16][128];
    int tid = threadIdx.x;
    for (int i = tid * 4; i < 128 * 128; i += 256 * 4) {
        *(float4*)(Wl + i) = *(const float4*)(W + i);
    }
    int row0 = blockIdx.x * 16;
    for (int i = tid * 4; i < 16 * 128; i += 256 * 4) {
        int r = i >> 7, d = i & 127;
        *(float4*)(&Xs[r][d]) = *(const float4*)(x + (long)(row0 + r) * EMB + d);
    }
    __syncthreads();
    int col = tid & 127;
    int rg = tid >> 7;
    float acc[8] = {0, 0, 0, 0, 0, 0, 0, 0};
    for (int k = 0; k < 128; ++k) {
        float w = Wl[k * 128 + col];
#pragma unroll
        for (int r = 0; r < 8; ++r) acc[r] += Xs[rg * 8 + r][k] * w;
    }
#pragma unroll
    for (int r = 0; r < 8; ++r)
        xw[(long)(row0 + rg * 8 + r) * EMB + col] = acc[r];
}

// ---------------- gather rows of h1 -> bf16 ----------------
__global__ void k_gather_h_bf16(const float* __restrict__ h1, const int* __restrict__ idx,
                                ushort* __restrict__ dst, int n) {
    int t = blockIdx.x * blockDim.x + threadIdx.x;
    int i = t >> 5;
    int d = (t & 31) << 2;
    if (i >= n) return;
    float4 v = *(const float4*)(h1 + (long)idx[i] * EMB + d);
    ushort4 o;
    o.x = f2bf(v.x);
    o.y = f2bf(v.y);
    o.z = f2bf(v.z);
    o.w = f2bf(v.w);
    *(ushort4*)(dst + (long)i * EMB + d) = o;
}

// ---------------- out[2048, 50000] = hb @ hi^T via MFMA bf16 ----------------
// block = 128x128 output tile, 4 waves in 2x2, each wave 64x64 (4x4 fragments of 16x16)
// K=128, both operands row-major K-contiguous -> symmetric fragment loads, no LDS.
__global__ __launch_bounds__(256) void k_score_mfma(const ushort* __restrict__ A,
                                                    const ushort* __restrict__ B,
                                                    float* __restrict__ C) {
    int wid = threadIdx.x >> 6;
    int lane = threadIdx.x & 63;
    int wm = wid >> 1, wn = wid & 1;
    long m0 = (long)blockIdx.y * 128 + wm * 64;
    long n0 = (long)blockIdx.x * 128 + wn * 64;
    int r = lane & 15;
    int kg = lane >> 4; // 0..3

    f32x4 acc[4][4] = {};
#pragma unroll
    for (int ks = 0; ks < 4; ++ks) {
        bf16x8 a[4], b[4];
#pragma unroll
        for (int mf = 0; mf < 4; ++mf) {
            long row = m0 + mf * 16 + r;
            a[mf] = *(const bf16x8*)(A + row * EMB + ks * 32 + kg * 8);
        }
#pragma unroll
        for (int nf = 0; nf < 4; ++nf) {
            long row = n0 + nf * 16 + r;
            if (row >= N_SCORE) row = N_SCORE - 1; // clamp: safe load, stores guarded
            b[nf] = *(const bf16x8*)(B + row * EMB + ks * 32 + kg * 8);
        }
#pragma unroll
        for (int mf = 0; mf < 4; ++mf)
#pragma unroll
            for (int nf = 0; nf < 4; ++nf)
                acc[mf][nf] = __builtin_amdgcn_mfma_f32_16x16x32_bf16(a[mf], b[nf], acc[mf][nf], 0, 0, 0);
    }
    // C/D layout: col = lane&15, row = (lane>>4)*4 + reg
#pragma unroll
    for (int mf = 0; mf < 4; ++mf) {
#pragma unroll
        for (int nf = 0; nf < 4; ++nf) {
            long col = n0 + nf * 16 + r;
            if (col < N_SCORE) {
#pragma unroll
                for (int j = 0; j < 4; ++j) {
                    long row = m0 + mf * 16 + kg * 4 + j;
                    C[row * N_SCORE + col] = acc[mf][nf][j];
                }
            }
        }
    }
}

extern "C" void kernel_launch(void* const* d_in, const int* in_sizes, int n_in,
                              void* d_out, int out_size, void* d_ws, size_t ws_size,
                              hipStream_t stream) {
    const float* emb_table      = (const float*)d_in[0];
    const float* W              = (const float*)d_in[1];
    const float* b              = (const float*)d_in[2];
    const float* sess_vals      = (const float*)d_in[3];
    const float* A_vals         = (const float*)d_in[4];
    const int*   batch_idxes    = (const int*)d_in[5];
    const int*   item_idxes     = (const int*)d_in[6];
    const int*   item_emb_idxes = (const int*)d_in[7];
    const int*   sess_rows      = (const int*)d_in[8];
    const int*   sess_cols      = (const int*)d_in[9];
    const int*   A_rows         = (const int*)d_in[10];
    const int*   A_cols         = (const int*)d_in[11];
    float* out = (float*)d_out;

    // -------- workspace layout (floats), 3 x 51.2MB regions --------
    float* ws = (float*)d_ws;
    float* x  = ws;                         // R0: [N_TOTAL,128]
    float* xw = ws + 12800000L;             // R1: [N_TOTAL,128]
    float* h1 = ws + 25600000L;             // R2: [N_TOTAL,128]

    float* x_session = x;
    float* x_item    = x + (long)N_SESS * EMB;

    // R2 overlays (dead before h1 produced): session CSR
    float* evS  = h1;
    int*   ecS  = (int*)(h1 + 500000);
    int*   cntS = (int*)(h1 + 1000000);
    int*   offS = (int*)(h1 + 1050004);

    // R0 overlays (dead after x@W): A CSR
    float* evA  = x;
    int*   ecA  = (int*)(x + 3200000);
    int*   cntA = (int*)(x + 6400000);
    int*   offA = (int*)(x + 6500004);

    // R1 overlays (dead after spmm2): bf16 score operands
    ushort* hb = (ushort*)xw;                       // [BATCH,128] bf16
    ushort* hi = hb + (long)BATCH * EMB;            // [N_SCORE,128] bf16

    // 1. session CSR build (into R2)
    hipMemsetAsync(cntS, 0, (size_t)N_SESS * sizeof(int), stream);
    k_count<<<(NNZ_S + 255) / 256, 256, 0, stream>>>(sess_rows, cntS, NNZ_S);
    k_scan_excl<<<1, 1024, 0, stream>>>(cntS, offS, N_SESS);
    k_place<<<(NNZ_S + 255) / 256, 256, 0, stream>>>(sess_rows, sess_cols, sess_vals,
                                                     offS, ecS, evS, NNZ_S);
    // 2. gather item embeddings
    k_gather_items<<<(N_ITEMS * 32 + 255) / 256, 256, 0, stream>>>(emb_table, item_emb_idxes, x_item);
    // 3. spmm1
    k_spmm_csr<<<(N_SESS + 3) / 4, 256, 0, stream>>>(offS, ecS, evS, x_item, x_session,
                                                     nullptr, N_SESS);
    // 4. xw = x @ W
    k_gemm_xw<<<N_TOTAL / 16, 256, 0, stream>>>(x, W, xw);
    // 5. A CSR build (into R0)
    hipMemsetAsync(cntA, 0, (size_t)N_TOTAL * sizeof(int), stream);
    k_count<<<(NNZ_A + 255) / 256, 256, 0, stream>>>(A_rows, cntA, NNZ_A);
    k_scan_excl<<<1, 1024, 0, stream>>>(cntA, offA, N_TOTAL);
    k_place<<<(NNZ_A + 255) / 256, 256, 0, stream>>>(A_rows, A_cols, A_vals,
                                                     offA, ecA, evA, NNZ_A);
    // 6. spmm2 + fused bias
    k_spmm_csr<<<(N_TOTAL + 3) / 4, 256, 0, stream>>>(offA, ecA, evA, xw, h1, b, N_TOTAL);
    // 7. gather hb, hi as bf16 (into R1)
    k_gather_h_bf16<<<(BATCH * 32 + 255) / 256, 256, 0, stream>>>(h1, batch_idxes, hb, BATCH);
    k_gather_h_bf16<<<(N_SCORE * 32 + 255) / 256, 256, 0, stream>>>(h1, item_idxes, hi, N_SCORE);
    // 8. out = hb @ hi^T via MFMA
    dim3 grid((N_SCORE + 127) / 128, BATCH / 128);
    k_score_mfma<<<grid, 256, 0, stream>>>(hb, hi, out);
}

// Round 4
// 823.878 us; speedup vs baseline: 8.5157x; 1.3241x over previous
//
#include <hip/hip_runtime.h>

#define EMB 128
#define N_ITEMS 50000
#define N_SESS 50000
#define N_TOTAL 100000
#define NNZ_S 500000
#define NNZ_A 3200000
#define BATCH 2048
#define N_SCORE 50000

typedef __attribute__((ext_vector_type(8))) short bf16x8;
typedef __attribute__((ext_vector_type(4))) float f32x4;

__device__ inline ushort f2bf(float f) {
    unsigned u = __float_as_uint(f);
    unsigned r = (u + 0x7fff + ((u >> 16) & 1)) >> 16;
    return (ushort)r;
}
__device__ inline float bflo(unsigned u) { return __uint_as_float(u << 16); }
__device__ inline float bfhi(unsigned u) { return __uint_as_float(u & 0xffff0000u); }

// ---------------- gather x_item = bf16(emb_table[item_emb_idxes]) ----------------
__global__ void k_gather_items_bf16(const float* __restrict__ emb, const int* __restrict__ idx,
                                    ushort* __restrict__ xb_item) {
    int t = blockIdx.x * blockDim.x + threadIdx.x;
    int i = t >> 5;
    int d = (t & 31) << 2;
    if (i >= N_ITEMS) return;
    float4 v = *(const float4*)(emb + (long)idx[i] * EMB + d);
    uint2 o;
    o.x = (unsigned)f2bf(v.x) | ((unsigned)f2bf(v.y) << 16);
    o.y = (unsigned)f2bf(v.z) | ((unsigned)f2bf(v.w) << 16);
    *(uint2*)(xb_item + (long)i * EMB + d) = o;
}

// ---------------- W -> Wt bf16 (transposed: Wt[n][k] = W[k][n]) ----------------
__global__ void k_convW(const float* __restrict__ W, ushort* __restrict__ Wt) {
    int i = blockIdx.x * 256 + threadIdx.x;
    if (i >= 128 * 128) return;
    int n = i >> 7, k = i & 127;
    Wt[n * 128 + k] = f2bf(W[k * 128 + n]);
}

// ---------------- CSR build: histogram ----------------
__global__ void k_count(const int* __restrict__ rows, int* __restrict__ cnt, int nnz) {
    int e = blockIdx.x * 256 + threadIdx.x;
    if (e < nnz) atomicAdd(&cnt[rows[e]], 1);
}

// ---------------- hierarchical scan, pass 1: per-block (1024) exclusive scan ----------------
__global__ __launch_bounds__(1024) void k_scan_block(const int* __restrict__ cnt,
                                                     int* __restrict__ excl,
                                                     int* __restrict__ bsum, int n) {
    __shared__ int wsum[16];
    int tid = threadIdx.x, lane = tid & 63, wid = tid >> 6;
    int i = blockIdx.x * 1024 + tid;
    int v = (i < n) ? cnt[i] : 0;
    int x = v;
#pragma unroll
    for (int s = 1; s < 64; s <<= 1) {
        int t = __shfl_up(x, s, 64);
        if (lane >= s) x += t;
    }
    if (lane == 63) wsum[wid] = x;
    __syncthreads();
    if (wid == 0) {
        int y = (lane < 16) ? wsum[lane] : 0;
#pragma unroll
        for (int s = 1; s < 16; s <<= 1) {
            int t = __shfl_up(y, s, 64);
            if (lane >= s) y += t;
        }
        if (lane < 16) wsum[lane] = y;
    }
    __syncthreads();
    int wofs = wid ? wsum[wid - 1] : 0;
    if (i < n) excl[i] = wofs + x - v;
    if (tid == 1023) bsum[blockIdx.x] = wsum[15];
}

// ---------------- pass 3: add scanned block prefix ----------------
__global__ __launch_bounds__(1024) void k_scan_add(int* __restrict__ excl,
                                                   const int* __restrict__ bsumx, int n) {
    int i = blockIdx.x * 1024 + threadIdx.x;
    if (i < n) excl[i] += bsumx[blockIdx.x];
}

// ---------------- CSR build: place edges packed (col, val) ----------------
__global__ void k_place(const int* __restrict__ rows, const int* __restrict__ cols,
                        const float* __restrict__ vals, int* __restrict__ off,
                        int2* __restrict__ edges, int nnz) {
    int e = blockIdx.x * 256 + threadIdx.x;
    if (e < nnz) {
        int r = rows[e];
        int pos = atomicAdd(&off[r], 1);
        edges[pos] = make_int2(cols[e], __float_as_int(vals[e]));
    }
}

// ---------------- CSR SpMM (bf16 src, fp32 acc, bf16 dst): one wave per row ----------------
__global__ __launch_bounds__(256) void k_spmm_csr_bf16(const int* __restrict__ off,
                                                       const int2* __restrict__ edges,
                                                       const ushort* __restrict__ src,
                                                       ushort* __restrict__ dst,
                                                       const float* __restrict__ bias,
                                                       int nrows) {
    int r = (blockIdx.x * 256 + threadIdx.x) >> 6;
    int lane = threadIdx.x & 63;
    if (r >= nrows) return;
    int begin = (r == 0) ? 0 : off[r - 1];
    int end = off[r];
    float2 acc = make_float2(0.f, 0.f);
    int e = begin;
    for (; e + 2 <= end; e += 2) {
        int2 e0 = edges[e], e1 = edges[e + 1];
        unsigned s0 = *(const unsigned*)(src + (long)e0.x * EMB + lane * 2);
        unsigned s1 = *(const unsigned*)(src + (long)e1.x * EMB + lane * 2);
        float v0 = __int_as_float(e0.y), v1 = __int_as_float(e1.y);
        acc.x += v0 * bflo(s0) + v1 * bflo(s1);
        acc.y += v0 * bfhi(s0) + v1 * bfhi(s1);
    }
    if (e < end) {
        int2 e0 = edges[e];
        unsigned s0 = *(const unsigned*)(src + (long)e0.x * EMB + lane * 2);
        float v0 = __int_as_float(e0.y);
        acc.x += v0 * bflo(s0);
        acc.y += v0 * bfhi(s0);
    }
    if (bias) {
        acc.x += bias[lane * 2];
        acc.y += bias[lane * 2 + 1];
    }
    unsigned o = (unsigned)f2bf(acc.x) | ((unsigned)f2bf(acc.y) << 16);
    *((unsigned*)(dst + (long)r * EMB) + lane) = o;
}

// ---------------- xw = xb @ Wt^T via MFMA (M=100000, N=128, K=128), bf16 out ----------------
__global__ __launch_bounds__(256) void k_xw_mfma(const ushort* __restrict__ A,
                                                 const ushort* __restrict__ Wt,
                                                 ushort* __restrict__ xw) {
    int wid = threadIdx.x >> 6;
    int lane = threadIdx.x & 63;
    int wm = wid >> 1, wn = wid & 1;
    long m0 = (long)blockIdx.x * 128 + wm * 64;
    int n0 = wn * 64;
    int r = lane & 15;
    int kg = lane >> 4;

    f32x4 acc[4][4] = {};
#pragma unroll
    for (int ks = 0; ks < 4; ++ks) {
        bf16x8 a[4], b[4];
#pragma unroll
        for (int mf = 0; mf < 4; ++mf) {
            long row = m0 + mf * 16 + r;
            if (row >= N_TOTAL) row = N_TOTAL - 1; // clamp, stores guarded
            a[mf] = *(const bf16x8*)(A + row * EMB + ks * 32 + kg * 8);
        }
#pragma unroll
        for (int nf = 0; nf < 4; ++nf) {
            int row = n0 + nf * 16 + r;
            b[nf] = *(const bf16x8*)(Wt + (long)row * EMB + ks * 32 + kg * 8);
        }
#pragma unroll
        for (int mf = 0; mf < 4; ++mf)
#pragma unroll
            for (int nf = 0; nf < 4; ++nf)
                acc[mf][nf] = __builtin_amdgcn_mfma_f32_16x16x32_bf16(a[mf], b[nf], acc[mf][nf], 0, 0, 0);
    }
#pragma unroll
    for (int mf = 0; mf < 4; ++mf) {
#pragma unroll
        for (int nf = 0; nf < 4; ++nf) {
            int col = n0 + nf * 16 + r;
#pragma unroll
            for (int j = 0; j < 4; ++j) {
                long row = m0 + mf * 16 + kg * 4 + j;
                if (row < N_TOTAL) xw[row * EMB + col] = f2bf(acc[mf][nf][j]);
            }
        }
    }
}

// ---------------- gather bf16 rows (256B row copy) ----------------
__global__ void k_gather_rows_bf16(const ushort* __restrict__ src, const int* __restrict__ idx,
                                   ushort* __restrict__ dst, int n) {
    int t = blockIdx.x * blockDim.x + threadIdx.x;
    int i = t >> 4;
    int d = (t & 15) << 3;
    if (i >= n) return;
    *(uint4*)(dst + (long)i * EMB + d) = *(const uint4*)(src + (long)idx[i] * EMB + d);
}

// ---------------- out[2048, 50000] = hb @ hi^T via MFMA bf16 ----------------
__global__ __launch_bounds__(256) void k_score_mfma(const ushort* __restrict__ A,
                                                    const ushort* __restrict__ B,
                                                    float* __restrict__ C) {
    int wid = threadIdx.x >> 6;
    int lane = threadIdx.x & 63;
    int wm = wid >> 1, wn = wid & 1;
    long m0 = (long)blockIdx.y * 128 + wm * 64;
    long n0 = (long)blockIdx.x * 128 + wn * 64;
    int r = lane & 15;
    int kg = lane >> 4;

    f32x4 acc[4][4] = {};
#pragma unroll
    for (int ks = 0; ks < 4; ++ks) {
        bf16x8 a[4], b[4];
#pragma unroll
        for (int mf = 0; mf < 4; ++mf) {
            long row = m0 + mf * 16 + r;
            a[mf] = *(const bf16x8*)(A + row * EMB + ks * 32 + kg * 8);
        }
#pragma unroll
        for (int nf = 0; nf < 4; ++nf) {
            long row = n0 + nf * 16 + r;
            if (row >= N_SCORE) row = N_SCORE - 1; // clamp, stores guarded
            b[nf] = *(const bf16x8*)(B + row * EMB + ks * 32 + kg * 8);
        }
#pragma unroll
        for (int mf = 0; mf < 4; ++mf)
#pragma unroll
            for (int nf = 0; nf < 4; ++nf)
                acc[mf][nf] = __builtin_amdgcn_mfma_f32_16x16x32_bf16(a[mf], b[nf], acc[mf][nf], 0, 0, 0);
    }
#pragma unroll
    for (int mf = 0; mf < 4; ++mf) {
#pragma unroll
        for (int nf = 0; nf < 4; ++nf) {
            long col = n0 + nf * 16 + r;
            if (col < N_SCORE) {
#pragma unroll
                for (int j = 0; j < 4; ++j) {
                    long row = m0 + mf * 16 + kg * 4 + j;
                    C[row * N_SCORE + col] = acc[mf][nf][j];
                }
            }
        }
    }
}

extern "C" void kernel_launch(void* const* d_in, const int* in_sizes, int n_in,
                              void* d_out, int out_size, void* d_ws, size_t ws_size,
                              hipStream_t stream) {
    const float* emb_table      = (const float*)d_in[0];
    const float* W              = (const float*)d_in[1];
    const float* b              = (const float*)d_in[2];
    const float* sess_vals      = (const float*)d_in[3];
    const float* A_vals         = (const float*)d_in[4];
    const int*   batch_idxes    = (const int*)d_in[5];
    const int*   item_idxes     = (const int*)d_in[6];
    const int*   item_emb_idxes = (const int*)d_in[7];
    const int*   sess_rows      = (const int*)d_in[8];
    const int*   sess_cols      = (const int*)d_in[9];
    const int*   A_rows         = (const int*)d_in[10];
    const int*   A_cols         = (const int*)d_in[11];
    float* out = (float*)d_out;

    // -------- workspace layout (bytes), total ~121 MB, no overlays --------
    char* base = (char*)d_ws;
    ushort* xb    = (ushort*)(base + 0);            // [N_TOTAL,128] bf16, 25.6MB
    ushort* xw    = (ushort*)(base + 25600000L);    // [N_TOTAL,128] bf16, 25.6MB
    ushort* h1    = (ushort*)(base + 51200000L);    // [N_TOTAL,128] bf16, 25.6MB
    int2*   edgA  = (int2*)  (base + 76800000L);    // 3.2M x 8B
    int2*   edgS  = (int2*)  (base + 102400000L);   // 500K x 8B
    int*    cntS  = (int*)   (base + 106400000L);   // 50000
    int*    offS  = (int*)   (base + 106600000L);   // 50000
    int*    cntA  = (int*)   (base + 106800000L);   // 100000
    int*    offA  = (int*)   (base + 107200000L);   // 100000
    int*    bsum  = (int*)   (base + 107600000L);   // 128
    int*    bsumx = (int*)   (base + 107600512L);   // 128
    int*    bdmy  = (int*)   (base + 107601024L);   // scratch
    ushort* Wt    = (ushort*)(base + 107601408L);   // 128x128 bf16
    ushort* hb    = (ushort*)(base + 107634176L);   // [BATCH,128] bf16
    ushort* hi    = (ushort*)(base + 108158464L);   // [N_SCORE,128] bf16

    ushort* xb_item = xb + (long)N_SESS * EMB;

    const int nbS = (N_SESS + 1023) / 1024;   // 49
    const int nbA = (N_TOTAL + 1023) / 1024;  // 98

    // ---- session CSR build ----
    hipMemsetAsync(cntS, 0, (size_t)N_SESS * sizeof(int), stream);
    k_count<<<(NNZ_S + 255) / 256, 256, 0, stream>>>(sess_rows, cntS, NNZ_S);
    k_scan_block<<<nbS, 1024, 0, stream>>>(cntS, offS, bsum, N_SESS);
    k_scan_block<<<1, 1024, 0, stream>>>(bsum, bsumx, bdmy, nbS);
    k_scan_add<<<nbS, 1024, 0, stream>>>(offS, bsumx, N_SESS);
    k_place<<<(NNZ_S + 255) / 256, 256, 0, stream>>>(sess_rows, sess_cols, sess_vals,
                                                     offS, edgS, NNZ_S);
    // ---- gather item embeddings (bf16) + W transpose ----
    k_gather_items_bf16<<<(N_ITEMS * 32 + 255) / 256, 256, 0, stream>>>(emb_table, item_emb_idxes, xb_item);
    k_convW<<<64, 256, 0, stream>>>(W, Wt);
    // ---- spmm1: session rows of xb ----
    k_spmm_csr_bf16<<<(N_SESS + 3) / 4, 256, 0, stream>>>(offS, edgS, xb_item, xb,
                                                          nullptr, N_SESS);
    // ---- xw = xb @ W (MFMA) ----
    k_xw_mfma<<<(N_TOTAL + 127) / 128, 256, 0, stream>>>(xb, Wt, xw);
    // ---- A CSR build ----
    hipMemsetAsync(cntA, 0, (size_t)N_TOTAL * sizeof(int), stream);
    k_count<<<(NNZ_A + 255) / 256, 256, 0, stream>>>(A_rows, cntA, NNZ_A);
    k_scan_block<<<nbA, 1024, 0, stream>>>(cntA, offA, bsum, N_TOTAL);
    k_scan_block<<<1, 1024, 0, stream>>>(bsum, bsumx, bdmy, nbA);
    k_scan_add<<<nbA, 1024, 0, stream>>>(offA, bsumx, N_TOTAL);
    k_place<<<(NNZ_A + 255) / 256, 256, 0, stream>>>(A_rows, A_cols, A_vals,
                                                     offA, edgA, NNZ_A);
    // ---- spmm2 + fused bias -> h1 (bf16) ----
    k_spmm_csr_bf16<<<(N_TOTAL + 3) / 4, 256, 0, stream>>>(offA, edgA, xw, h1, b, N_TOTAL);
    // ---- gather hb, hi ----
    k_gather_rows_bf16<<<(BATCH * 16 + 255) / 256, 256, 0, stream>>>(h1, batch_idxes, hb, BATCH);
    k_gather_rows_bf16<<<(N_SCORE * 16 + 255) / 256, 256, 0, stream>>>(h1, item_idxes, hi, N_SCORE);
    // ---- score ----
    dim3 grid((N_SCORE + 127) / 128, BATCH / 128);
    k_score_mfma<<<grid, 256, 0, stream>>>(hb, hi, out);
}